// Round 15
// baseline (824.311 us; speedup 1.0000x reference)
//
#include <hip/hip_runtime.h>

// Problem constants
#define NMAT 50
#define BATCH 128
#define FDIM 1024
#define HDIM 4096
#define ROWS 6400            // BATCH*NMAT
#define PSIZE 320000         // BATCH*NMAT*NMAT
#define HINF 1e18

// ws layout (bytes):
//   Mpart : [0, 10240000)            fp64 [4][6400][50]; psi64 overwrites p0
//   W1Thi : [10240000, +8388608)     bf16 [4096][1024]  (W1 transposed, hi)
//   W1Tlo : [18628608, +8388608)     bf16 [4096][1024]  (lo)
//   xhi   : [27017216, +13107200)    bf16 [6400][1024]
//   xlo   : [40124416, +13107200)
//   hbuf  : [53231616, ...)          fp32 [max_rows][4096]
#define WS_M_OFF    0
#define WS_W1H_OFF  10240000LL
#define WS_W1L_OFF  18628608LL
#define WS_XH_OFF   27017216LL
#define WS_XL_OFF   40124416LL
#define WS_H_OFF    53231616LL
#define WS_MIN      (WS_H_OFF + 128LL * HDIM * 4)

typedef __bf16 bf16x8 __attribute__((ext_vector_type(8)));
typedef float f32x4 __attribute__((ext_vector_type(4)));

__device__ __forceinline__ float bf16_to_f32(unsigned short h) {
  return __uint_as_float(((unsigned int)h) << 16);
}
__device__ __forceinline__ unsigned short f32_to_bf16(float f) {
  unsigned int u = __float_as_uint(f);
  u += 0x7FFFu + ((u >> 16) & 1u);   // RNE
  return (unsigned short)(u >> 16);
}

// ---------------- split_x: x fp32 -> xhi/xlo bf16 (one pass) ----------------
__global__ __launch_bounds__(256) void split_x(
    const float* __restrict__ X, unsigned short* __restrict__ Xhi,
    unsigned short* __restrict__ Xlo) {
  int i = blockIdx.x * 256 + threadIdx.x;      // over float4 units: 1638400
  const float4 v = ((const float4*)X)[i];
  ushort4 h, l;
  h.x = f32_to_bf16(v.x); l.x = f32_to_bf16(v.x - bf16_to_f32(h.x));
  h.y = f32_to_bf16(v.y); l.y = f32_to_bf16(v.y - bf16_to_f32(h.y));
  h.z = f32_to_bf16(v.z); l.z = f32_to_bf16(v.z - bf16_to_f32(h.z));
  h.w = f32_to_bf16(v.w); l.w = f32_to_bf16(v.w - bf16_to_f32(h.w));
  ((ushort4*)Xhi)[i] = h;
  ((ushort4*)Xlo)[i] = l;
}

// ---------------- split_w1t: W1 [1024][4096] -> W1Thi/Tlo [4096][1024] ------
__global__ __launch_bounds__(256) void split_w1t(
    const float* __restrict__ W1, unsigned short* __restrict__ Thi,
    unsigned short* __restrict__ Tlo) {
  __shared__ ushort2 tile[64][65];
  int k0 = (blockIdx.x & 15) * 64;   // 1024/64 k-tiles
  int n0 = (blockIdx.x >> 4) * 64;   // 4096/64 n-tiles
  int c = threadIdx.x & 63, r0 = threadIdx.x >> 6;
#pragma unroll
  for (int i = 0; i < 16; ++i) {
    int r = r0 + i * 4;
    float f = W1[(size_t)(k0 + r) * HDIM + n0 + c];
    unsigned short h = f32_to_bf16(f);
    unsigned short l = f32_to_bf16(f - bf16_to_f32(h));
    tile[r][c] = (ushort2){h, l};
  }
  __syncthreads();
#pragma unroll
  for (int i = 0; i < 16; ++i) {
    int r = r0 + i * 4;
    ushort2 hl = tile[c][r];
    Thi[(size_t)(n0 + r) * FDIM + k0 + c] = hl.x;
    Tlo[(size_t)(n0 + r) * FDIM + k0 + c] = hl.y;
  }
}

// ---------------- GEMM1 (split-bf16 MFMA, pre-split operands) ---------------
// h = leaky(x@W1+b1) = hi*hi + hi*lo + lo*hi (fp32 MFMA accumulate).
// 128x128 tile, BK=32, 4 waves. LDS [kgroup][row][8]: all stores/reads
// lane-contiguous (conflict-free, verified round 14: SQ_LDS_BANK_CONFLICT=0).
// C/D mapping per m89: col=lane&15, row=(lane>>4)*4+reg.
__global__ __launch_bounds__(256) void gemm1_mfma(
    const unsigned short* __restrict__ Xhi,   // chunk base [rows][1024]
    const unsigned short* __restrict__ Xlo,
    const unsigned short* __restrict__ Thi,   // [4096][1024] (W1^T)
    const unsigned short* __restrict__ Tlo,
    const float* __restrict__ b1,
    float* __restrict__ Hout) {               // chunk base [rows][4096]
  __shared__ __align__(16) unsigned short Ah[4 * 128 * 8];
  __shared__ __align__(16) unsigned short Al[4 * 128 * 8];
  __shared__ __align__(16) unsigned short Bh[4 * 128 * 8];
  __shared__ __align__(16) unsigned short Bl[4 * 128 * 8];
  int t = threadIdx.x;
  int wave = t >> 6, lane = t & 63;
  int nt = blockIdx.x & 31;      // 4096/128 n-tiles
  int mt = blockIdx.x >> 5;
  int m0 = mt * 128, n0 = nt * 128;
  int wm = wave >> 1, wn = wave & 1;
  int fr = lane & 15, fg = lane >> 4;
  int mA = lane, nB = lane;       // staging rows for half 0; +64 for half 1

  f32x4 acc[4][4];
#pragma unroll
  for (int i = 0; i < 4; ++i)
#pragma unroll
    for (int j = 0; j < 4; ++j) acc[i][j] = (f32x4){0.f, 0.f, 0.f, 0.f};

  for (int k0 = 0; k0 < FDIM; k0 += 32) {
    // issue all 8 staging loads before the barrier (overlap with prior MFMA)
    int ka = k0 + wave * 8;
    uint4 a0h = *(const uint4*)&Xhi[(size_t)(m0 + mA) * FDIM + ka];
    uint4 a1h = *(const uint4*)&Xhi[(size_t)(m0 + mA + 64) * FDIM + ka];
    uint4 a0l = *(const uint4*)&Xlo[(size_t)(m0 + mA) * FDIM + ka];
    uint4 a1l = *(const uint4*)&Xlo[(size_t)(m0 + mA + 64) * FDIM + ka];
    uint4 b0h = *(const uint4*)&Thi[(size_t)(n0 + nB) * FDIM + ka];
    uint4 b1h = *(const uint4*)&Thi[(size_t)(n0 + nB + 64) * FDIM + ka];
    uint4 b0l = *(const uint4*)&Tlo[(size_t)(n0 + nB) * FDIM + ka];
    uint4 b1l = *(const uint4*)&Tlo[(size_t)(n0 + nB + 64) * FDIM + ka];
    __syncthreads();               // prior fragment reads complete
    int base0 = (wave * 128 + lane) * 8;
    int base1 = (wave * 128 + lane + 64) * 8;
    *(uint4*)&Ah[base0] = a0h;  *(uint4*)&Ah[base1] = a1h;
    *(uint4*)&Al[base0] = a0l;  *(uint4*)&Al[base1] = a1l;
    *(uint4*)&Bh[base0] = b0h;  *(uint4*)&Bh[base1] = b1h;
    *(uint4*)&Bl[base0] = b0l;  *(uint4*)&Bl[base1] = b1l;
    __syncthreads();
    bf16x8 ah[4], al[4], bh[4], bl[4];
#pragma unroll
    for (int i = 0; i < 4; ++i) {
      int arow = (fg * 128 + wm * 64 + i * 16 + fr) * 8;
      ah[i] = *(const bf16x8*)&Ah[arow];
      al[i] = *(const bf16x8*)&Al[arow];
      int brow = (fg * 128 + wn * 64 + i * 16 + fr) * 8;
      bh[i] = *(const bf16x8*)&Bh[brow];
      bl[i] = *(const bf16x8*)&Bl[brow];
    }
#pragma unroll
    for (int i = 0; i < 4; ++i)
#pragma unroll
      for (int j = 0; j < 4; ++j) {
        acc[i][j] = __builtin_amdgcn_mfma_f32_16x16x32_bf16(ah[i], bh[j], acc[i][j], 0, 0, 0);
        acc[i][j] = __builtin_amdgcn_mfma_f32_16x16x32_bf16(ah[i], bl[j], acc[i][j], 0, 0, 0);
        acc[i][j] = __builtin_amdgcn_mfma_f32_16x16x32_bf16(al[i], bh[j], acc[i][j], 0, 0, 0);
      }
  }

  // Epilogue: col=lane&15, row=(lane>>4)*4+reg [m89-verified]
  int colb = n0 + wn * 64 + fr;
  int rowb = m0 + wm * 64 + fg * 4;
#pragma unroll
  for (int j = 0; j < 4; ++j) {
    float bias = b1[colb + j * 16];
#pragma unroll
    for (int i = 0; i < 4; ++i)
#pragma unroll
      for (int r = 0; r < 4; ++r) {
        float v = acc[i][j][r] + bias;
        v = v >= 0.0f ? v : 0.01f * v;
        Hout[(size_t)(rowb + i * 16 + r) * HDIM + colb + j * 16] = v;
      }
  }
}

// ---------------- GEMM2: Mpart[kz] = h @ W2 (fp64, split-K=4) ---------------
__global__ __launch_bounds__(256) void gemm2_kernel(
    const float* __restrict__ hchunk,        // chunk base [rows][4096] fp32
    const float* __restrict__ W2,            // [4096][50] fp32
    double* __restrict__ Mpart,              // [4][6400][50]
    int row0) {
  __shared__ __align__(16) float hs[32 * 64];
  __shared__ float w2s[64 * 52];
  int t = threadIdx.x;
  int c = t & 63, g = t >> 6;                // rows g, g+4, ..., g+28
  int kz = blockIdx.y;
  double acc[8] = {0, 0, 0, 0, 0, 0, 0, 0};
  const float* hbase = hchunk + (size_t)blockIdx.x * 32 * HDIM;

  for (int k0 = kz * 1024; k0 < kz * 1024 + 1024; k0 += 64) {
    __syncthreads();
    {
      int row = t >> 3, seg = (t & 7) * 8;
      const float4* src = (const float4*)(hbase + (size_t)row * HDIM + k0 + seg);
      float4 v0 = src[0], v1 = src[1];
      float4* dst = (float4*)(hs + row * 64 + seg);
      dst[0] = v0; dst[1] = v1;
    }
    for (int idx = t; idx < 3200; idx += 256) {     // 64 k x 50 c, coalesced
      int cc = idx % 50, kk = idx / 50;
      w2s[kk * 52 + cc] = W2[(size_t)k0 * NMAT + idx];
    }
    __syncthreads();
    if (c < NMAT) {
#pragma unroll 4
      for (int kk = 0; kk < 64; kk += 2) {
        double w0 = (double)w2s[kk * 52 + c];
        double w1 = (double)w2s[kk * 52 + 52 + c];
#pragma unroll
        for (int i = 0; i < 8; ++i) {
          float2 hv = *(const float2*)&hs[(g + i * 4) * 64 + kk];   // broadcast
          acc[i] = fma((double)hv.x, w0, acc[i]);
          acc[i] = fma((double)hv.y, w1, acc[i]);
        }
      }
    }
  }
  if (c < NMAT) {
    double* Mout = Mpart + (size_t)kz * PSIZE;
#pragma unroll
    for (int i = 0; i < 8; ++i)
      Mout[(size_t)(row0 + blockIdx.x * 32 + g + i * 4) * NMAT + c] = acc[i];
  }
}

// ---------------- Sinkhorn (fp64): merge partials, exp, 5x row/col norm -----
__global__ __launch_bounds__(64) void sinkhorn_kernel(
    double* __restrict__ Mpart, const float* __restrict__ b2,
    float* __restrict__ out_psi, float* __restrict__ out_X) {
  int b = blockIdx.x, lane = threadIdx.x;
  __shared__ double P[2500];
  __shared__ double rs[50];
  const size_t base = (size_t)b * 2500;
  for (int e = lane; e < 2500; e += 64) {
    double m = Mpart[base + e] + Mpart[PSIZE + base + e] +
               Mpart[2 * PSIZE + base + e] + Mpart[3 * PSIZE + base + e];
    m += (double)b2[e % 50];
    m = m >= 0.0 ? m : 0.01 * m;      // leaky_relu in fp64
    P[e] = exp(m);                    // TAU = 1.0
  }
  __syncthreads();
  for (int it = 0; it < 5; ++it) {
    if (lane < 50) { double s = 0; for (int j = 0; j < 50; ++j) s += P[lane * 50 + j]; rs[lane] = s; }
    __syncthreads();
    for (int e = lane; e < 2500; e += 64) P[e] /= rs[e / 50];   // axis=2
    __syncthreads();
    if (lane < 50) { double s = 0; for (int r = 0; r < 50; ++r) s += P[r * 50 + lane]; rs[lane] = s; }
    __syncthreads();
    for (int e = lane; e < 2500; e += 64) P[e] /= rs[e % 50];   // axis=1
    __syncthreads();
  }
  for (int e = lane; e < 2500; e += 64) {
    double pv = P[e];
    Mpart[base + e] = pv;             // psi64 in-place (partial-0 region)
    float f = (float)pv;
    out_psi[base + e] = f;
    out_X[base + e] = f;              // ALPHA=1.0 => X == psi exactly
  }
}

// ---------------- Hungarian (exact replica incl. dead-minv), fp64 -----------
__global__ __launch_bounds__(64) void hungarian_kernel(
    const double* __restrict__ psi64, float* __restrict__ out_perms,
    float* __restrict__ out_dist) {
  int b = blockIdx.x, lane = threadIdx.x;
  __shared__ double cost[2500];
  __shared__ double u[51];
  __shared__ int p[51];
  __shared__ int wayl[51];
  const double* P = psi64 + (size_t)b * 2500;
  for (int e = lane; e < 2500; e += 64) cost[e] = -P[e];
  if (lane < 51) { u[lane] = 0.0; p[lane] = 0; }
  __syncthreads();
  double v = 0.0;                      // v[lane+1]
  bool lactive = lane < NMAT;

  for (int i = 1; i <= NMAT; ++i) {
    bool used = false;
    int way = 0;
    int j0 = 0, j1 = 0;
    for (int guard = 0; guard < 64; ++guard) {   // defensive cap (normally <=51)
      if (lane == j0 - 1) used = true;           // used[j0] = True (j0>=1)
      int i0 = (j0 == 0) ? i : p[j0];
      double ui0 = u[i0];
      double cand = HINF;
      if (lactive && !used) {
        cand = cost[(i0 - 1) * NMAT + lane] - ui0 - v;
        way = j0;                                // way set for ALL free cols (dead-minv)
      }
      double m = cand;
#pragma unroll
      for (int s = 32; s > 0; s >>= 1) {
        double o = __shfl_xor(m, s, 64);
        m = (o < m) ? o : m;
      }
      unsigned long long bal = __ballot(cand == m);
      j1 = (int)__builtin_ctzll(bal) + 1;        // np.argmin tie-break: lowest j
      double delta = m;
      __syncthreads();
      if (used) { v -= delta; u[p[lane + 1]] += delta; }   // distinct rows, no race
      if (lane == 63) u[i] += delta;                       // j=0 column: p[0]=i
      __syncthreads();
      j0 = j1;
      if (p[j0] == 0) break;
    }
    if (lactive) wayl[lane + 1] = way;
    __syncthreads();
    if (lane == 0) {                   // augment (serial, path <= 50)
      int j = j1;
      while (j != 0) {
        int jw = wayl[j];
        p[j] = (jw == 0) ? i : p[jw];
        j = jw;
      }
    }
    __syncthreads();
  }

  // perms one-hot + dist (fp32 outputs)
  size_t pbase = (size_t)b * 2500;
  for (int e = lane; e < 2500; e += 64) out_perms[pbase + e] = 0.0f;
  __syncthreads();
  double val = 0.0;
  if (lactive) {
    int row = p[lane + 1] - 1;
    if (row < 0) row = 0;              // defensive clamp (provably unreachable)
    if (row > 49) row = 49;
    out_perms[pbase + (size_t)row * NMAT + lane] = 1.0f;
    val = P[(size_t)row * NMAT + lane];
  }
#pragma unroll
  for (int s = 32; s > 0; s >>= 1) val += __shfl_xor(val, s, 64);
  if (lane == 0) out_dist[b] = (float)(val / (double)NMAT);
}

// ---------------------------------------------------------------------------
extern "C" void kernel_launch(void* const* d_in, const int* in_sizes, int n_in,
                              void* d_out, int out_size, void* d_ws, size_t ws_size,
                              hipStream_t stream) {
  const float* x  = (const float*)d_in[0];   // fp32 per the reference dtypes
  const float* W1 = (const float*)d_in[1];
  const float* b1 = (const float*)d_in[2];
  const float* W2 = (const float*)d_in[3];
  const float* b2 = (const float*)d_in[4];
  float* out = (float*)d_out;                // outputs float32 (round-8/11 finding)
  float* out_psi   = out;
  float* out_perms = out + PSIZE;
  float* out_X     = out + 2 * PSIZE;
  float* out_dist  = out + 3 * PSIZE;

  if (ws_size < (size_t)WS_MIN) return;

  char* ws = (char*)d_ws;
  double* Mpart = (double*)(ws + WS_M_OFF);
  unsigned short* W1Thi = (unsigned short*)(ws + WS_W1H_OFF);
  unsigned short* W1Tlo = (unsigned short*)(ws + WS_W1L_OFF);
  unsigned short* xhi   = (unsigned short*)(ws + WS_XH_OFF);
  unsigned short* xlo   = (unsigned short*)(ws + WS_XL_OFF);
  float* hbuf = (float*)(ws + WS_H_OFF);
  long long avail = (long long)ws_size - WS_H_OFF;
  int max_rows = (int)(avail / (HDIM * 4));
  max_rows = (max_rows / 128) * 128;
  if (max_rows > ROWS) max_rows = ROWS;

  hipLaunchKernelGGL(split_x, dim3(6400 * 1024 / 4 / 256), dim3(256), 0, stream,
                     x, xhi, xlo);
  hipLaunchKernelGGL(split_w1t, dim3(1024), dim3(256), 0, stream,
                     W1, W1Thi, W1Tlo);
  for (int r0 = 0; r0 < ROWS; r0 += max_rows) {
    int rows = (ROWS - r0 < max_rows) ? (ROWS - r0) : max_rows;
    hipLaunchKernelGGL(gemm1_mfma, dim3((rows / 128) * 32), dim3(256), 0, stream,
                       xhi + (size_t)r0 * FDIM, xlo + (size_t)r0 * FDIM,
                       W1Thi, W1Tlo, b1, hbuf);
    hipLaunchKernelGGL(gemm2_kernel, dim3(rows / 32, 4), dim3(256), 0, stream,
                       hbuf, W2, Mpart, r0);
  }
  hipLaunchKernelGGL(sinkhorn_kernel, dim3(BATCH), dim3(64), 0, stream,
                     Mpart, b2, out_psi, out_X);
  hipLaunchKernelGGL(hungarian_kernel, dim3(BATCH), dim3(64), 0, stream,
                     Mpart, out_perms, out_dist);
}